// Round 5
// baseline (4703.475 us; speedup 1.0000x reference)
//
#include <hip/hip_runtime.h>

#define DIN   256
#define HID   8192
#define BATCH 8192
#define TOPK  32
#define NSEL  64          // superset size for exact re-rank
#define BM    32
#define BN    256
#define BK    64
#define NQ    128         // staging pieces: 32 chunk-cols x 4 k-pieces
#define AS_LD 264         // 528 B row stride
#define BS_LD 72          // 144 B row stride
#define DN_LD 257         // dense chunk stride (f32)
#define XF_LD 260

typedef __bf16 bf16x8 __attribute__((ext_vector_type(8)));
typedef float f32x4v __attribute__((ext_vector_type(4)));

__device__ __forceinline__ unsigned short f2bf(float f) {
  unsigned x = __builtin_bit_cast(unsigned, f);
  x = x + 0x7fffu + ((x >> 16) & 1u);   // RNE, finite only
  return (unsigned short)(x >> 16);
}
__device__ __forceinline__ unsigned pkbf(float a, float b) {
  return (unsigned)f2bf(a) | ((unsigned)f2bf(b) << 16);
}

union U1 { unsigned short As[BM][AS_LD]; float dense[BM][DN_LD]; };  // 32896 B
union U2 { unsigned short Bs[BN][BS_LD]; float xf[BM][XF_LD]; };     // 36864 B

__global__ __launch_bounds__(512, 2) void sae_fused(
    const float* __restrict__ x,    const float* __restrict__ Wenc,
    const float* __restrict__ benc, const float* __restrict__ Wdec,
    const float* __restrict__ bdec, float* __restrict__ out)
{
  __shared__ __align__(16) U1 u1;
  __shared__ __align__(16) U2 u2;
  __shared__ float tv[BM][NSEL];
  __shared__ int   ti[BM][NSEL];

  const int tid  = (int)threadIdx.x;
  const int wave = tid >> 6;
  const int lane = tid & 63;
  const int quad = lane >> 4;
  const int ln15 = lane & 15;
  const int mb   = (int)blockIdx.x * BM;

  // ---- Phase 0: stage bf16(x - b_dec) rows into LDS ----
  {
    const int r = tid >> 4, seg = tid & 15;
    const float* xs = x + (size_t)(mb + r) * DIN + seg * 16;
    const float* bs = bdec + seg * 16;
    #pragma unroll
    for (int j = 0; j < 4; ++j) {
      float4 xv = *(const float4*)(xs + 4 * j);
      float4 bv = *(const float4*)(bs + 4 * j);
      unsigned short* dst = &u1.As[r][seg * 16 + 4 * j];
      dst[0] = f2bf(xv.x - bv.x); dst[1] = f2bf(xv.y - bv.y);
      dst[2] = f2bf(xv.z - bv.z); dst[3] = f2bf(xv.w - bv.w);
    }
  }
  __syncthreads();

  // A-fragments (verified 16x16x32 layout): A[m=lane&15][k=quad*8+j]
  bf16x8 afrag[2][8];
  #pragma unroll
  for (int mt = 0; mt < 2; ++mt)
    #pragma unroll
    for (int gk = 0; gk < 8; ++gk)
      afrag[mt][gk] = *(const bf16x8*)&u1.As[mt * 16 + ln15][gk * 32 + quad * 8];
  __syncthreads();

  // ---- init per-row top-64 heaps ----
  {
    float* tvf = &tv[0][0];
    int*   tif = &ti[0][0];
    for (int j = tid; j < BM * NSEL; j += 512) { tvf[j] = 0.0f; tif[j] = -1; }
  }

  // ---- software-pipelined W_enc staging (f32 -> bf16 LDS) ----
  float4 streg[8];
  #pragma unroll
  for (int i = 0; i < 4; ++i) {
    int unit = i * 512 + tid;
    int r = unit >> 3, c16 = unit & 7;
    const float* src = Wenc + (size_t)r * DIN + c16 * 8;   // piece 0: c=0,p=0
    streg[2 * i]     = *(const float4*)src;
    streg[2 * i + 1] = *(const float4*)(src + 4);
  }

  f32x4v acc[2][2];
  #pragma unroll
  for (int mt = 0; mt < 2; ++mt)
    #pragma unroll
    for (int nt = 0; nt < 2; ++nt)
      #pragma unroll
      for (int i = 0; i < 4; ++i) acc[mt][nt][i] = 0.0f;

  for (int q = 0; q < NQ; ++q) {
    const int c = q >> 2, p = q & 3;
    __syncthreads();   // previous piece's MFMA reads done -> Bs free
    #pragma unroll
    for (int i = 0; i < 4; ++i) {
      int unit = i * 512 + tid;
      int r = unit >> 3, c16 = unit & 7;
      float4 lo = streg[2 * i], hi = streg[2 * i + 1];
      uint4 wv;
      wv.x = pkbf(lo.x, lo.y); wv.y = pkbf(lo.z, lo.w);
      wv.z = pkbf(hi.x, hi.y); wv.w = pkbf(hi.z, hi.w);
      *(uint4*)&u2.Bs[r][c16 * 8] = wv;
    }
    if (q + 1 < NQ) {
      const int cn = (q + 1) >> 2, pn = (q + 1) & 3;
      #pragma unroll
      for (int i = 0; i < 4; ++i) {
        int unit = i * 512 + tid;
        int r = unit >> 3, c16 = unit & 7;
        const float* src = Wenc + (size_t)(cn * BN + r) * DIN + pn * BK + c16 * 8;
        streg[2 * i]     = *(const float4*)src;
        streg[2 * i + 1] = *(const float4*)(src + 4);
      }
    }
    __syncthreads();   // Bs ready
    // B-fragments: B[n=lane&15][k=quad*8+j] from Bs[n][k] (B^T layout)
    #pragma unroll
    for (int nt = 0; nt < 2; ++nt) {
      #pragma unroll
      for (int kl = 0; kl < 2; ++kl) {
        bf16x8 bfrag = *(const bf16x8*)&u2.Bs[wave * 32 + nt * 16 + ln15][kl * 32 + quad * 8];
        acc[0][nt] = __builtin_amdgcn_mfma_f32_16x16x32_bf16(afrag[0][p * 2 + kl], bfrag, acc[0][nt], 0, 0, 0);
        acc[1][nt] = __builtin_amdgcn_mfma_f32_16x16x32_bf16(afrag[1][p * 2 + kl], bfrag, acc[1][nt], 0, 0, 0);
      }
    }
    if (p == 3) {
      // ---- dense chunk epilogue: +b_enc, relu, write 32x256 scores ----
      // verified C/D layout: col=lane&15, row=quad*4+reg
      #pragma unroll
      for (int mt = 0; mt < 2; ++mt) {
        #pragma unroll
        for (int nt = 0; nt < 2; ++nt) {
          const int col = wave * 32 + nt * 16 + ln15;
          const float be = benc[c * BN + col];
          #pragma unroll
          for (int i = 0; i < 4; ++i) {
            const int row = mt * 16 + quad * 4 + i;
            float v = acc[mt][nt][i] + be;
            u1.dense[row][col] = v > 0.0f ? v : 0.0f;
            acc[mt][nt][i] = 0.0f;
          }
        }
      }
      __syncthreads();
      if (tid < BM) {   // serial per-row scan into 64-entry min-heap
        float* tvr = tv[tid];
        int*   tir = ti[tid];
        float root = tvr[0];
        const int hbase = c * BN;
        for (int cc2 = 0; cc2 < BN; ++cc2) {
          float v = u1.dense[tid][cc2];
          if (v > root) {
            int idx = hbase + cc2;
            int pos = 0;
            while (true) {
              int c1 = 2 * pos + 1;
              if (c1 >= NSEL) break;
              int c2 = c1 + 1;
              int cm = (c2 < NSEL && tv[tid][c2] < tv[tid][c1]) ? c2 : c1;
              if (!(tvr[cm] < v)) break;
              tvr[pos] = tvr[cm]; tir[pos] = tir[cm]; pos = cm;
            }
            tvr[pos] = v; tir[pos] = idx;
            root = tvr[0];
          }
        }
      }
      __syncthreads();
    }
  }

  // ---- Phase 2: exact f64 re-rank of the 64 candidates per row ----
  {  // stage exact f32 sae_in rows (reuses Bs region)
    const int r = tid >> 4, seg = tid & 15;
    const float* xs = x + (size_t)(mb + r) * DIN + seg * 16;
    const float* bs = bdec + seg * 16;
    #pragma unroll
    for (int j = 0; j < 4; ++j) {
      float4 xv = *(const float4*)(xs + 4 * j);
      float4 bv = *(const float4*)(bs + 4 * j);
      float4 d;
      d.x = xv.x - bv.x; d.y = xv.y - bv.y; d.z = xv.z - bv.z; d.w = xv.w - bv.w;
      *(float4*)&u2.xf[r][seg * 16 + 4 * j] = d;
    }
  }
  __syncthreads();
  {  // 2048 (row,cand) pairs; 4 threads per pair split K
    const int sub = tid & 3, pidx = tid >> 2;
    for (int j = 0; j < 16; ++j) {
      int pp = j * 128 + pidx;
      int row = pp >> 6, cand = pp & 63;
      int h = ti[row][cand];
      double accd = 0.0;
      if (h >= 0) {
        const float* wp = Wenc + (size_t)h * DIN + sub * 64;
        const float* xp = &u2.xf[row][sub * 64];
        #pragma unroll
        for (int kk = 0; kk < 16; ++kk) {
          float4 w  = *(const float4*)(wp + 4 * kk);
          float4 xv = *(const float4*)(xp + 4 * kk);
          accd += (double)xv.x * (double)w.x;
          accd += (double)xv.y * (double)w.y;
          accd += (double)xv.z * (double)w.z;
          accd += (double)xv.w * (double)w.w;
        }
      }
      accd += __shfl_down(accd, 2, 4);
      accd += __shfl_down(accd, 1, 4);
      if (sub == 0) {
        float ev = 0.0f;
        if (h >= 0) {
          ev = (float)accd + benc[h];
          ev = ev > 0.0f ? ev : 0.0f;   // relu before ranking (matches ref)
        }
        tv[row][cand] = ev;
      }
    }
  }
  __syncthreads();
  if (tid < BM) {  // exact top-32 of 64 (value desc, idx asc — np top_k order)
    float* tvr = tv[tid];
    int*   tir = ti[tid];
    for (int s = 0; s < TOPK; ++s) {
      float bv = tvr[s]; int bi = tir[s]; int bp = s;
      for (int t2 = s + 1; t2 < NSEL; ++t2) {
        float v2 = tvr[t2]; int i2 = tir[t2];
        if (v2 > bv || (v2 == bv && (unsigned)i2 < (unsigned)bi)) {
          bv = v2; bi = i2; bp = t2;
        }
      }
      if (bp != s) {
        tvr[bp] = tvr[s]; tir[bp] = tir[s];
        tvr[s] = bv; tir[s] = bi;
      }
    }
  }
  __syncthreads();

  // ---- decode: out[b,:] = sum z_k * W_dec[idx_k,:] + b_dec  (all f32) ----
  {
    const int r = tid >> 4, seg = tid & 15, d0 = seg * 16;
    float od[16];
    #pragma unroll
    for (int j = 0; j < 4; ++j) {
      float4 b = *(const float4*)(bdec + d0 + 4 * j);
      od[4 * j] = b.x; od[4 * j + 1] = b.y; od[4 * j + 2] = b.z; od[4 * j + 3] = b.w;
    }
    for (int s = 0; s < TOPK; ++s) {
      float v = tv[r][s];
      if (!(v > 0.0f)) break;    // sorted desc
      int h = ti[r][s];
      const float* wp = Wdec + (size_t)h * DIN + d0;
      #pragma unroll
      for (int j = 0; j < 4; ++j) {
        float4 w = *(const float4*)(wp + 4 * j);
        od[4 * j]     += v * w.x;
        od[4 * j + 1] += v * w.y;
        od[4 * j + 2] += v * w.z;
        od[4 * j + 3] += v * w.w;
      }
    }
    float* op = out + (size_t)(mb + r) * DIN + d0;
    #pragma unroll
    for (int j = 0; j < 4; ++j) {
      float4 o;
      o.x = od[4 * j]; o.y = od[4 * j + 1]; o.z = od[4 * j + 2]; o.w = od[4 * j + 3];
      *(float4*)(op + 4 * j) = o;
    }
  }
}

extern "C" void kernel_launch(void* const* d_in, const int* in_sizes, int n_in,
                              void* d_out, int out_size, void* d_ws, size_t ws_size,
                              hipStream_t stream) {
  const float* x    = (const float*)d_in[0];
  const float* Wenc = (const float*)d_in[1];
  const float* benc = (const float*)d_in[2];
  const float* Wdec = (const float*)d_in[3];
  const float* bdec = (const float*)d_in[4];
  float* out = (float*)d_out;

  dim3 grid(BATCH / BM);   // 256 blocks, one per CU
  dim3 block(512);         // 8 waves
  sae_fused<<<grid, block, 0, stream>>>(x, Wenc, benc, Wdec, bdec, out);
}

// Round 6
// 699.264 us; speedup vs baseline: 6.7263x; 6.7263x over previous
//
#include <hip/hip_runtime.h>

#define DIN   256
#define HID   8192
#define BATCH 8192
#define TOPK  32
#define NSEL  64          // superset size for exact re-rank
#define BM    32
#define BN    256
#define BK    64
#define NQ    128         // staging pieces: 32 chunk-cols x 4 k-pieces
#define AS_LD 264         // 528 B row stride
#define BS_LD 72          // 144 B row stride
#define XF_LD 260
#define TW    24          // tournament pops per wave per row
#define MG    (8*TW)      // 192 merged candidates per row
#define MG_LD 193
#define LLEN  8           // per-(thread,row) register list length

typedef __bf16 bf16x8 __attribute__((ext_vector_type(8)));
typedef float f32x4v __attribute__((ext_vector_type(4)));

__device__ __forceinline__ unsigned short f2bf(float f) {
  unsigned x = __builtin_bit_cast(unsigned, f);
  x = x + 0x7fffu + ((x >> 16) & 1u);   // RNE, finite only
  return (unsigned short)(x >> 16);
}
__device__ __forceinline__ unsigned pkbf(float a, float b) {
  return (unsigned)f2bf(a) | ((unsigned)f2bf(b) << 16);
}

union U1 { unsigned short As[BM][AS_LD]; unsigned mg[BM][MG_LD]; };  // 24.7 KB
union U2 { unsigned short Bs[BN][BS_LD]; float xf[BM][XF_LD]; };     // 36.9 KB

__global__ __launch_bounds__(512, 2) void sae_fused(
    const float* __restrict__ x,    const float* __restrict__ Wenc,
    const float* __restrict__ benc, const float* __restrict__ Wdec,
    const float* __restrict__ bdec, float* __restrict__ out)
{
  __shared__ __align__(16) U1 u1;
  __shared__ __align__(16) U2 u2;
  __shared__ float tv[BM][NSEL];
  __shared__ int   ti[BM][NSEL];

  const int tid  = (int)threadIdx.x;
  const int wave = tid >> 6;
  const int lane = tid & 63;
  const int quad = lane >> 4;
  const int ln15 = lane & 15;
  const int mb   = (int)blockIdx.x * BM;

  // ---- Phase 0: stage bf16(x - b_dec) rows into LDS ----
  {
    const int r = tid >> 4, seg = tid & 15;
    const float* xs = x + (size_t)(mb + r) * DIN + seg * 16;
    const float* bs = bdec + seg * 16;
    #pragma unroll
    for (int j = 0; j < 4; ++j) {
      float4 xv = *(const float4*)(xs + 4 * j);
      float4 bv = *(const float4*)(bs + 4 * j);
      unsigned short* dst = &u1.As[r][seg * 16 + 4 * j];
      dst[0] = f2bf(xv.x - bv.x); dst[1] = f2bf(xv.y - bv.y);
      dst[2] = f2bf(xv.z - bv.z); dst[3] = f2bf(xv.w - bv.w);
    }
  }
  __syncthreads();

  // A-fragments (verified 16x16x32 layout): A[m=lane&15][k=quad*8+j]
  bf16x8 afrag[2][8];
  #pragma unroll
  for (int mt = 0; mt < 2; ++mt)
    #pragma unroll
    for (int gk = 0; gk < 8; ++gk)
      afrag[mt][gk] = *(const bf16x8*)&u1.As[mt * 16 + ln15][gk * 32 + quad * 8];
  __syncthreads();

  // ---- private top-LLEN key lists, one per owned row (slot s = mt*4+i) ----
  // key = (bf16(v)<<16) | (8191-h): u32 order == (value desc, idx asc)
  unsigned lst[8][LLEN];
  #pragma unroll
  for (int s = 0; s < 8; ++s)
    #pragma unroll
    for (int j = 0; j < LLEN; ++j) lst[s][j] = 0u;

  // ---- software-pipelined W_enc staging (f32 -> bf16 LDS) ----
  float4 streg[8];
  #pragma unroll
  for (int i = 0; i < 4; ++i) {
    int unit = i * 512 + tid;
    int r = unit >> 3, c16 = unit & 7;
    const float* src = Wenc + (size_t)r * DIN + c16 * 8;   // piece 0: c=0,p=0
    streg[2 * i]     = *(const float4*)src;
    streg[2 * i + 1] = *(const float4*)(src + 4);
  }

  f32x4v acc[2][2];
  #pragma unroll
  for (int mt = 0; mt < 2; ++mt)
    #pragma unroll
    for (int nt = 0; nt < 2; ++nt)
      #pragma unroll
      for (int i = 0; i < 4; ++i) acc[mt][nt][i] = 0.0f;

  for (int q = 0; q < NQ; ++q) {
    const int c = q >> 2, p = q & 3;
    __syncthreads();   // previous piece's MFMA reads done -> Bs free
    #pragma unroll
    for (int i = 0; i < 4; ++i) {
      int unit = i * 512 + tid;
      int r = unit >> 3, c16 = unit & 7;
      float4 lo = streg[2 * i], hi = streg[2 * i + 1];
      uint4 wv;
      wv.x = pkbf(lo.x, lo.y); wv.y = pkbf(lo.z, lo.w);
      wv.z = pkbf(hi.x, hi.y); wv.w = pkbf(hi.z, hi.w);
      *(uint4*)&u2.Bs[r][c16 * 8] = wv;
    }
    if (q + 1 < NQ) {
      const int cn = (q + 1) >> 2, pn = (q + 1) & 3;
      #pragma unroll
      for (int i = 0; i < 4; ++i) {
        int unit = i * 512 + tid;
        int r = unit >> 3, c16 = unit & 7;
        const float* src = Wenc + (size_t)(cn * BN + r) * DIN + pn * BK + c16 * 8;
        streg[2 * i]     = *(const float4*)src;
        streg[2 * i + 1] = *(const float4*)(src + 4);
      }
    }
    __syncthreads();   // Bs ready
    // B-fragments: B[n=lane&15][k=quad*8+j] from Bs[n][k] (B^T layout)
    #pragma unroll
    for (int nt = 0; nt < 2; ++nt) {
      #pragma unroll
      for (int kl = 0; kl < 2; ++kl) {
        bf16x8 bfrag = *(const bf16x8*)&u2.Bs[wave * 32 + nt * 16 + ln15][kl * 32 + quad * 8];
        acc[0][nt] = __builtin_amdgcn_mfma_f32_16x16x32_bf16(afrag[0][p * 2 + kl], bfrag, acc[0][nt], 0, 0, 0);
        acc[1][nt] = __builtin_amdgcn_mfma_f32_16x16x32_bf16(afrag[1][p * 2 + kl], bfrag, acc[1][nt], 0, 0, 0);
      }
    }
    if (p == 3) {
      // ---- chunk epilogue: +b_enc, relu, register sorted-list insert ----
      // C/D layout: col=lane&15, row=quad*4+reg (+16*mt)
      #pragma unroll
      for (int mt = 0; mt < 2; ++mt) {
        #pragma unroll
        for (int nt = 0; nt < 2; ++nt) {
          const int h  = c * BN + wave * 32 + nt * 16 + ln15;
          const float be = benc[h];
          const unsigned idxpart = (unsigned)(8191 - h);
          #pragma unroll
          for (int i = 0; i < 4; ++i) {
            const int s = mt * 4 + i;
            float v = acc[mt][nt][i] + be;
            acc[mt][nt][i] = 0.0f;
            v = v > 0.0f ? v : 0.0f;
            unsigned k = ((unsigned)f2bf(v) << 16) | idxpart;
            if (k > lst[s][LLEN - 1]) {     // beats my list's min -> insert
              #pragma unroll
              for (int j = 0; j < LLEN; ++j) {
                unsigned cur = lst[s][j];
                bool put = k > cur;
                lst[s][j] = put ? k : cur;
                k = put ? cur : k;
              }
            }
          }
        }
      }
    }
  }

  // ---- Stage 1: per-wave 16-lane shuffle tournament -> top-TW per row ----
  #pragma unroll
  for (int s = 0; s < 8; ++s) {
    const int row = (s >> 2) * 16 + quad * 4 + (s & 3);
    unsigned head = lst[s][0];
    for (int t = 0; t < TW; ++t) {
      unsigned m = head;
      #pragma unroll
      for (int d = 1; d < 16; d <<= 1) {
        unsigned o = __shfl_xor(m, d, 16);
        m = o > m ? o : m;
      }
      if (head == m) {        // I own the max (keys unique): pop + publish
        u1.mg[row][wave * TW + t] = m;
        #pragma unroll
        for (int j = 0; j < LLEN - 1; ++j) lst[s][j] = lst[s][j + 1];
        lst[s][LLEN - 1] = 0u;
      }
      head = lst[s][0];
    }
  }
  __syncthreads();

  // ---- Stage 2: exact rank-select top-64 of 192 per row (keys unique) ----
  {
    const int row = tid >> 4, lane16 = tid & 15;
    unsigned myk[12];
    int rank[12];
    #pragma unroll
    for (int j = 0; j < 12; ++j) {
      myk[j]  = u1.mg[row][lane16 + 16 * j];
      rank[j] = 0;
    }
    for (int e = 0; e < MG; ++e) {
      unsigned k2 = u1.mg[row][e];
      #pragma unroll
      for (int j = 0; j < 12; ++j) rank[j] += (k2 > myk[j]) ? 1 : 0;
    }
    #pragma unroll
    for (int j = 0; j < 12; ++j)
      if (rank[j] < NSEL) ti[row][rank[j]] = 8191 - (int)(myk[j] & 0xFFFFu);
  }

  // ---- stage exact f32 sae_in rows (overlays Bs; loop is done) ----
  {
    const int r = tid >> 4, seg = tid & 15;
    const float* xs = x + (size_t)(mb + r) * DIN + seg * 16;
    const float* bs = bdec + seg * 16;
    #pragma unroll
    for (int j = 0; j < 4; ++j) {
      float4 xv = *(const float4*)(xs + 4 * j);
      float4 bv = *(const float4*)(bs + 4 * j);
      float4 d;
      d.x = xv.x - bv.x; d.y = xv.y - bv.y; d.z = xv.z - bv.z; d.w = xv.w - bv.w;
      *(float4*)&u2.xf[r][seg * 16 + 4 * j] = d;
    }
  }
  __syncthreads();

  // ---- Phase 2: exact f64 re-rank of the 64 candidates per row ----
  {  // 2048 (row,cand) pairs; 4 threads per pair split K
    const int sub = tid & 3, pidx = tid >> 2;
    for (int j = 0; j < 16; ++j) {
      int pp = j * 128 + pidx;
      int row = pp >> 6, cand = pp & 63;
      int h = ti[row][cand];
      const float* wp = Wenc + (size_t)h * DIN + sub * 64;
      const float* xp = &u2.xf[row][sub * 64];
      double accd = 0.0;
      #pragma unroll
      for (int kk = 0; kk < 16; ++kk) {
        float4 w  = *(const float4*)(wp + 4 * kk);
        float4 xv = *(const float4*)(xp + 4 * kk);
        accd += (double)xv.x * (double)w.x;
        accd += (double)xv.y * (double)w.y;
        accd += (double)xv.z * (double)w.z;
        accd += (double)xv.w * (double)w.w;
      }
      accd += __shfl_down(accd, 2, 4);
      accd += __shfl_down(accd, 1, 4);
      if (sub == 0) {
        float ev = (float)accd + benc[h];
        ev = ev > 0.0f ? ev : 0.0f;   // relu before ranking (matches ref)
        tv[row][cand] = ev;
      }
    }
  }
  __syncthreads();
  if (tid < BM) {  // exact top-32 of 64 (value desc, idx asc — np top_k order)
    float* tvr = tv[tid];
    int*   tir = ti[tid];
    for (int s = 0; s < TOPK; ++s) {
      float bv = tvr[s]; int bi = tir[s]; int bp = s;
      for (int t2 = s + 1; t2 < NSEL; ++t2) {
        float v2 = tvr[t2]; int i2 = tir[t2];
        if (v2 > bv || (v2 == bv && (unsigned)i2 < (unsigned)bi)) {
          bv = v2; bi = i2; bp = t2;
        }
      }
      if (bp != s) {
        tvr[bp] = tvr[s]; tir[bp] = tir[s];
        tvr[s] = bv; tir[s] = bi;
      }
    }
  }
  __syncthreads();

  // ---- decode: out[b,:] = sum z_k * W_dec[idx_k,:] + b_dec  (all f32) ----
  {
    const int r = tid >> 4, seg = tid & 15, d0 = seg * 16;
    float od[16];
    #pragma unroll
    for (int j = 0; j < 4; ++j) {
      float4 b = *(const float4*)(bdec + d0 + 4 * j);
      od[4 * j] = b.x; od[4 * j + 1] = b.y; od[4 * j + 2] = b.z; od[4 * j + 3] = b.w;
    }
    for (int s = 0; s < TOPK; ++s) {
      float v = tv[r][s];
      if (!(v > 0.0f)) break;    // sorted desc
      int h = ti[r][s];
      const float* wp = Wdec + (size_t)h * DIN + d0;
      #pragma unroll
      for (int j = 0; j < 4; ++j) {
        float4 w = *(const float4*)(wp + 4 * j);
        od[4 * j]     += v * w.x;
        od[4 * j + 1] += v * w.y;
        od[4 * j + 2] += v * w.z;
        od[4 * j + 3] += v * w.w;
      }
    }
    float* op = out + (size_t)(mb + r) * DIN + d0;
    #pragma unroll
    for (int j = 0; j < 4; ++j) {
      float4 o;
      o.x = od[4 * j]; o.y = od[4 * j + 1]; o.z = od[4 * j + 2]; o.w = od[4 * j + 3];
      *(float4*)(op + 4 * j) = o;
    }
  }
}

extern "C" void kernel_launch(void* const* d_in, const int* in_sizes, int n_in,
                              void* d_out, int out_size, void* d_ws, size_t ws_size,
                              hipStream_t stream) {
  const float* x    = (const float*)d_in[0];
  const float* Wenc = (const float*)d_in[1];
  const float* benc = (const float*)d_in[2];
  const float* Wdec = (const float*)d_in[3];
  const float* bdec = (const float*)d_in[4];
  float* out = (float*)d_out;

  dim3 grid(BATCH / BM);   // 256 blocks, one per CU
  dim3 block(512);         // 8 waves
  sae_fused<<<grid, block, 0, stream>>>(x, Wenc, benc, Wdec, bdec, out);
}

// Round 7
// 695.537 us; speedup vs baseline: 6.7624x; 1.0054x over previous
//
#include <hip/hip_runtime.h>

#define DIN   256
#define HID   8192
#define BATCH 8192
#define TOPK  32
#define NSEL  64          // superset size for exact re-rank
#define BM    32
#define BN    256
#define BK    64
#define NQ    128         // staging pieces: 32 chunk-cols x 4 k-pieces
#define AS_LD 264         // 528 B row stride
#define BS_LD 72          // 144 B row stride
#define XF_LD 260
#define TW    24          // tournament pops per wave per row
#define MG    (8*TW)      // 192 merged candidates per row
#define MG_LD 193
#define LLEN  8           // per-(thread,row) register list length

typedef __bf16 bf16x8 __attribute__((ext_vector_type(8)));
typedef float f32x4v __attribute__((ext_vector_type(4)));

__device__ __forceinline__ unsigned short f2bf(float f) {
  unsigned x = __builtin_bit_cast(unsigned, f);
  x = x + 0x7fffu + ((x >> 16) & 1u);   // RNE, finite only
  return (unsigned short)(x >> 16);
}
__device__ __forceinline__ unsigned pkbf(float a, float b) {
  return (unsigned)f2bf(a) | ((unsigned)f2bf(b) << 16);
}

union U1 { unsigned short As[BM][AS_LD]; unsigned mg[BM][MG_LD]; };  // 24.7 KB
union U2 { unsigned short Bs[BN][BS_LD]; float xf[BM][XF_LD]; };     // 36.9 KB

// NOTE: __launch_bounds__(512) (no waves arg): 512-thread block needs 2
// waves/SIMD -> 256-VGPR cap. The previous (512,2) meant 2 waves/EU ->
// 128-VGPR cap -> spilled lst[]/afrag[] to scratch (WRITE_SIZE 40MB vs
// 8MB output, 77% stall). Keep everything register-resident.
__global__ __launch_bounds__(512) void sae_fused(
    const float* __restrict__ x,    const float* __restrict__ Wenc,
    const float* __restrict__ benc, const float* __restrict__ Wdec,
    const float* __restrict__ bdec, float* __restrict__ out)
{
  __shared__ __align__(16) U1 u1;
  __shared__ __align__(16) U2 u2;
  __shared__ float tv[BM][NSEL];
  __shared__ int   ti[BM][NSEL];

  const int tid  = (int)threadIdx.x;
  const int wave = tid >> 6;
  const int lane = tid & 63;
  const int quad = lane >> 4;
  const int ln15 = lane & 15;
  const int mb   = (int)blockIdx.x * BM;

  // ---- Phase 0: stage bf16(x - b_dec) rows into LDS ----
  {
    const int r = tid >> 4, seg = tid & 15;
    const float* xs = x + (size_t)(mb + r) * DIN + seg * 16;
    const float* bs = bdec + seg * 16;
    #pragma unroll
    for (int j = 0; j < 4; ++j) {
      float4 xv = *(const float4*)(xs + 4 * j);
      float4 bv = *(const float4*)(bs + 4 * j);
      unsigned short* dst = &u1.As[r][seg * 16 + 4 * j];
      dst[0] = f2bf(xv.x - bv.x); dst[1] = f2bf(xv.y - bv.y);
      dst[2] = f2bf(xv.z - bv.z); dst[3] = f2bf(xv.w - bv.w);
    }
  }
  __syncthreads();

  // A-fragments (verified 16x16x32 layout): A[m=lane&15][k=quad*8+j]
  bf16x8 afrag[2][8];
  #pragma unroll
  for (int mt = 0; mt < 2; ++mt)
    #pragma unroll
    for (int gk = 0; gk < 8; ++gk)
      afrag[mt][gk] = *(const bf16x8*)&u1.As[mt * 16 + ln15][gk * 32 + quad * 8];
  __syncthreads();

  // ---- private top-LLEN key lists, one per owned row (slot s = mt*4+i) ----
  // key = (bf16(v)<<16) | (8191-h): u32 order == (value desc, idx asc)
  unsigned lst[8][LLEN];
  #pragma unroll
  for (int s = 0; s < 8; ++s)
    #pragma unroll
    for (int j = 0; j < LLEN; ++j) lst[s][j] = 0u;

  // ---- software-pipelined W_enc staging (f32 -> bf16 LDS) ----
  float4 streg[8];
  #pragma unroll
  for (int i = 0; i < 4; ++i) {
    int unit = i * 512 + tid;
    int r = unit >> 3, c16 = unit & 7;
    const float* src = Wenc + (size_t)r * DIN + c16 * 8;   // piece 0: c=0,p=0
    streg[2 * i]     = *(const float4*)src;
    streg[2 * i + 1] = *(const float4*)(src + 4);
  }

  f32x4v acc[2][2];
  #pragma unroll
  for (int mt = 0; mt < 2; ++mt)
    #pragma unroll
    for (int nt = 0; nt < 2; ++nt)
      #pragma unroll
      for (int i = 0; i < 4; ++i) acc[mt][nt][i] = 0.0f;

  for (int q = 0; q < NQ; ++q) {
    const int c = q >> 2, p = q & 3;
    __syncthreads();   // previous piece's MFMA reads done -> Bs free
    #pragma unroll
    for (int i = 0; i < 4; ++i) {
      int unit = i * 512 + tid;
      int r = unit >> 3, c16 = unit & 7;
      float4 lo = streg[2 * i], hi = streg[2 * i + 1];
      uint4 wv;
      wv.x = pkbf(lo.x, lo.y); wv.y = pkbf(lo.z, lo.w);
      wv.z = pkbf(hi.x, hi.y); wv.w = pkbf(hi.z, hi.w);
      *(uint4*)&u2.Bs[r][c16 * 8] = wv;
    }
    if (q + 1 < NQ) {
      const int cn = (q + 1) >> 2, pn = (q + 1) & 3;
      #pragma unroll
      for (int i = 0; i < 4; ++i) {
        int unit = i * 512 + tid;
        int r = unit >> 3, c16 = unit & 7;
        const float* src = Wenc + (size_t)(cn * BN + r) * DIN + pn * BK + c16 * 8;
        streg[2 * i]     = *(const float4*)src;
        streg[2 * i + 1] = *(const float4*)(src + 4);
      }
    }
    __syncthreads();   // Bs ready
    // B-fragments: B[n=lane&15][k=quad*8+j] from Bs[n][k] (B^T layout)
    #pragma unroll
    for (int nt = 0; nt < 2; ++nt) {
      #pragma unroll
      for (int kl = 0; kl < 2; ++kl) {
        bf16x8 bfrag = *(const bf16x8*)&u2.Bs[wave * 32 + nt * 16 + ln15][kl * 32 + quad * 8];
        acc[0][nt] = __builtin_amdgcn_mfma_f32_16x16x32_bf16(afrag[0][p * 2 + kl], bfrag, acc[0][nt], 0, 0, 0);
        acc[1][nt] = __builtin_amdgcn_mfma_f32_16x16x32_bf16(afrag[1][p * 2 + kl], bfrag, acc[1][nt], 0, 0, 0);
      }
    }
    if (p == 3) {
      // ---- chunk epilogue: +b_enc, relu, register sorted-list insert ----
      // C/D layout: col=lane&15, row=quad*4+reg (+16*mt)
      #pragma unroll
      for (int mt = 0; mt < 2; ++mt) {
        #pragma unroll
        for (int nt = 0; nt < 2; ++nt) {
          const int h  = c * BN + wave * 32 + nt * 16 + ln15;
          const float be = benc[h];
          const unsigned idxpart = (unsigned)(8191 - h);
          #pragma unroll
          for (int i = 0; i < 4; ++i) {
            const int s = mt * 4 + i;
            float v = acc[mt][nt][i] + be;
            acc[mt][nt][i] = 0.0f;
            v = v > 0.0f ? v : 0.0f;
            unsigned k = ((unsigned)f2bf(v) << 16) | idxpart;
            if (k > lst[s][LLEN - 1]) {     // beats my list's min -> insert
              #pragma unroll
              for (int j = 0; j < LLEN; ++j) {
                unsigned cur = lst[s][j];
                bool put = k > cur;
                lst[s][j] = put ? k : cur;
                k = put ? cur : k;
              }
            }
          }
        }
      }
    }
  }

  // ---- Stage 1: per-wave 16-lane shuffle tournament -> top-TW per row ----
  #pragma unroll
  for (int s = 0; s < 8; ++s) {
    const int row = (s >> 2) * 16 + quad * 4 + (s & 3);
    unsigned head = lst[s][0];
    for (int t = 0; t < TW; ++t) {
      unsigned m = head;
      #pragma unroll
      for (int d = 1; d < 16; d <<= 1) {
        unsigned o = __shfl_xor(m, d, 16);
        m = o > m ? o : m;
      }
      if (head == m) {        // I own the max (keys unique): pop + publish
        u1.mg[row][wave * TW + t] = m;
        #pragma unroll
        for (int j = 0; j < LLEN - 1; ++j) lst[s][j] = lst[s][j + 1];
        lst[s][LLEN - 1] = 0u;
      }
      head = lst[s][0];
    }
  }
  __syncthreads();

  // ---- Stage 2: exact rank-select top-64 of 192 per row (keys unique) ----
  {
    const int row = tid >> 4, lane16 = tid & 15;
    unsigned myk[12];
    int rank[12];
    #pragma unroll
    for (int j = 0; j < 12; ++j) {
      myk[j]  = u1.mg[row][lane16 + 16 * j];
      rank[j] = 0;
    }
    for (int e = 0; e < MG; ++e) {
      unsigned k2 = u1.mg[row][e];
      #pragma unroll
      for (int j = 0; j < 12; ++j) rank[j] += (k2 > myk[j]) ? 1 : 0;
    }
    #pragma unroll
    for (int j = 0; j < 12; ++j)
      if (rank[j] < NSEL) ti[row][rank[j]] = 8191 - (int)(myk[j] & 0xFFFFu);
  }

  // ---- stage exact f32 sae_in rows (overlays Bs; loop is done) ----
  {
    const int r = tid >> 4, seg = tid & 15;
    const float* xs = x + (size_t)(mb + r) * DIN + seg * 16;
    const float* bs = bdec + seg * 16;
    #pragma unroll
    for (int j = 0; j < 4; ++j) {
      float4 xv = *(const float4*)(xs + 4 * j);
      float4 bv = *(const float4*)(bs + 4 * j);
      float4 d;
      d.x = xv.x - bv.x; d.y = xv.y - bv.y; d.z = xv.z - bv.z; d.w = xv.w - bv.w;
      *(float4*)&u2.xf[r][seg * 16 + 4 * j] = d;
    }
  }
  __syncthreads();

  // ---- Phase 2: exact f64 re-rank of the 64 candidates per row ----
  {  // 2048 (row,cand) pairs; 4 threads per pair split K
    const int sub = tid & 3, pidx = tid >> 2;
    for (int j = 0; j < 16; ++j) {
      int pp = j * 128 + pidx;
      int row = pp >> 6, cand = pp & 63;
      int h = ti[row][cand];
      const float* wp = Wenc + (size_t)h * DIN + sub * 64;
      const float* xp = &u2.xf[row][sub * 64];
      double accd = 0.0;
      #pragma unroll
      for (int kk = 0; kk < 16; ++kk) {
        float4 w  = *(const float4*)(wp + 4 * kk);
        float4 xv = *(const float4*)(xp + 4 * kk);
        accd += (double)xv.x * (double)w.x;
        accd += (double)xv.y * (double)w.y;
        accd += (double)xv.z * (double)w.z;
        accd += (double)xv.w * (double)w.w;
      }
      accd += __shfl_down(accd, 2, 4);
      accd += __shfl_down(accd, 1, 4);
      if (sub == 0) {
        float ev = (float)accd + benc[h];
        ev = ev > 0.0f ? ev : 0.0f;   // relu before ranking (matches ref)
        tv[row][cand] = ev;
      }
    }
  }
  __syncthreads();
  if (tid < BM) {  // exact top-32 of 64 (value desc, idx asc — np top_k order)
    float* tvr = tv[tid];
    int*   tir = ti[tid];
    for (int s = 0; s < TOPK; ++s) {
      float bv = tvr[s]; int bi = tir[s]; int bp = s;
      for (int t2 = s + 1; t2 < NSEL; ++t2) {
        float v2 = tvr[t2]; int i2 = tir[t2];
        if (v2 > bv || (v2 == bv && (unsigned)i2 < (unsigned)bi)) {
          bv = v2; bi = i2; bp = t2;
        }
      }
      if (bp != s) {
        tvr[bp] = tvr[s]; tir[bp] = tir[s];
        tvr[s] = bv; tir[s] = bi;
      }
    }
  }
  __syncthreads();

  // ---- decode: out[b,:] = sum z_k * W_dec[idx_k,:] + b_dec  (all f32) ----
  {
    const int r = tid >> 4, seg = tid & 15, d0 = seg * 16;
    float od[16];
    #pragma unroll
    for (int j = 0; j < 4; ++j) {
      float4 b = *(const float4*)(bdec + d0 + 4 * j);
      od[4 * j] = b.x; od[4 * j + 1] = b.y; od[4 * j + 2] = b.z; od[4 * j + 3] = b.w;
    }
    for (int s = 0; s < TOPK; ++s) {
      float v = tv[r][s];
      if (!(v > 0.0f)) break;    // sorted desc
      int h = ti[r][s];
      const float* wp = Wdec + (size_t)h * DIN + d0;
      #pragma unroll
      for (int j = 0; j < 4; ++j) {
        float4 w = *(const float4*)(wp + 4 * j);
        od[4 * j]     += v * w.x;
        od[4 * j + 1] += v * w.y;
        od[4 * j + 2] += v * w.z;
        od[4 * j + 3] += v * w.w;
      }
    }
    float* op = out + (size_t)(mb + r) * DIN + d0;
    #pragma unroll
    for (int j = 0; j < 4; ++j) {
      float4 o;
      o.x = od[4 * j]; o.y = od[4 * j + 1]; o.z = od[4 * j + 2]; o.w = od[4 * j + 3];
      *(float4*)(op + 4 * j) = o;
    }
  }
}

extern "C" void kernel_launch(void* const* d_in, const int* in_sizes, int n_in,
                              void* d_out, int out_size, void* d_ws, size_t ws_size,
                              hipStream_t stream) {
  const float* x    = (const float*)d_in[0];
  const float* Wenc = (const float*)d_in[1];
  const float* benc = (const float*)d_in[2];
  const float* Wdec = (const float*)d_in[3];
  const float* bdec = (const float*)d_in[4];
  float* out = (float*)d_out;

  dim3 grid(BATCH / BM);   // 256 blocks, one per CU
  dim3 block(512);         // 8 waves
  sae_fused<<<grid, block, 0, stream>>>(x, Wenc, benc, Wdec, bdec, out);
}

// Round 8
// 694.597 us; speedup vs baseline: 6.7715x; 1.0014x over previous
//
#include <hip/hip_runtime.h>

#define DIN   256
#define HID   8192
#define BATCH 8192
#define TOPK  32
#define NSEL  64          // superset size for exact re-rank
#define BM    32
#define BN    256
#define BK    64
#define NQ    128         // staging pieces: 32 chunk-cols x 4 k-pieces
#define AS_LD 264         // 528 B row stride
#define BS_LD 72          // 144 B row stride
#define XF_LD 260
#define TW    24          // tournament pops per wave per row
#define MG    (8*TW)      // 192 merged candidates per row
#define MG_LD 193
#define LLEN  8           // per-(thread,row) register list length

typedef __bf16 bf16x8 __attribute__((ext_vector_type(8)));
typedef float f32x4v __attribute__((ext_vector_type(4)));

__device__ __forceinline__ unsigned short f2bf(float f) {
  unsigned x = __builtin_bit_cast(unsigned, f);
  x = x + 0x7fffu + ((x >> 16) & 1u);   // RNE, finite only
  return (unsigned short)(x >> 16);
}
__device__ __forceinline__ unsigned pkbf(float a, float b) {
  return (unsigned)f2bf(a) | ((unsigned)f2bf(b) << 16);
}

union U1 { unsigned short As[BM][AS_LD]; unsigned mg[BM][MG_LD]; };  // 24.7 KB
union U2 { unsigned short Bs[BN][BS_LD]; float xf[BM][XF_LD]; };     // 36.9 KB

// NOTE: VGPR history — (512,2): 92 VGPR + spill; (512): STILL 92 VGPR + spill
// (WRITE_SIZE 41MB vs 8.4MB output = lst[] in scratch; FETCH 530MB = scratch
// reloads thrashing L2). The allocation is driven by the scheduler's
// occupancy heuristic, not launch bounds. amdgpu_waves_per_eu(2,2) pins the
// target at 2 waves/EU (the max possible for a resident 512-thread block
// anyway) so the allocator may use up to ~256 VGPRs -> no spill.
__global__ __launch_bounds__(512) __attribute__((amdgpu_waves_per_eu(2, 2)))
void sae_fused(
    const float* __restrict__ x,    const float* __restrict__ Wenc,
    const float* __restrict__ benc, const float* __restrict__ Wdec,
    const float* __restrict__ bdec, float* __restrict__ out)
{
  __shared__ __align__(16) U1 u1;
  __shared__ __align__(16) U2 u2;
  __shared__ float tv[BM][NSEL];
  __shared__ int   ti[BM][NSEL];

  const int tid  = (int)threadIdx.x;
  const int wave = tid >> 6;
  const int lane = tid & 63;
  const int quad = lane >> 4;
  const int ln15 = lane & 15;
  const int mb   = (int)blockIdx.x * BM;

  // ---- Phase 0: stage bf16(x - b_dec) rows into LDS ----
  {
    const int r = tid >> 4, seg = tid & 15;
    const float* xs = x + (size_t)(mb + r) * DIN + seg * 16;
    const float* bs = bdec + seg * 16;
    #pragma unroll
    for (int j = 0; j < 4; ++j) {
      float4 xv = *(const float4*)(xs + 4 * j);
      float4 bv = *(const float4*)(bs + 4 * j);
      unsigned short* dst = &u1.As[r][seg * 16 + 4 * j];
      dst[0] = f2bf(xv.x - bv.x); dst[1] = f2bf(xv.y - bv.y);
      dst[2] = f2bf(xv.z - bv.z); dst[3] = f2bf(xv.w - bv.w);
    }
  }
  __syncthreads();

  // A-fragments (verified 16x16x32 layout): A[m=lane&15][k=quad*8+j]
  bf16x8 afrag[2][8];
  #pragma unroll
  for (int mt = 0; mt < 2; ++mt)
    #pragma unroll
    for (int gk = 0; gk < 8; ++gk)
      afrag[mt][gk] = *(const bf16x8*)&u1.As[mt * 16 + ln15][gk * 32 + quad * 8];
  __syncthreads();

  // ---- private top-LLEN key lists, one per owned row (slot s = mt*4+i) ----
  // key = (bf16(v)<<16) | (8191-h): u32 order == (value desc, idx asc)
  unsigned lst[8][LLEN];
  #pragma unroll
  for (int s = 0; s < 8; ++s)
    #pragma unroll
    for (int j = 0; j < LLEN; ++j) lst[s][j] = 0u;

  // ---- software-pipelined W_enc staging (f32 -> bf16 LDS) ----
  float4 streg[8];
  #pragma unroll
  for (int i = 0; i < 4; ++i) {
    int unit = i * 512 + tid;
    int r = unit >> 3, c16 = unit & 7;
    const float* src = Wenc + (size_t)r * DIN + c16 * 8;   // piece 0: c=0,p=0
    streg[2 * i]     = *(const float4*)src;
    streg[2 * i + 1] = *(const float4*)(src + 4);
  }

  f32x4v acc[2][2];
  #pragma unroll
  for (int mt = 0; mt < 2; ++mt)
    #pragma unroll
    for (int nt = 0; nt < 2; ++nt)
      #pragma unroll
      for (int i = 0; i < 4; ++i) acc[mt][nt][i] = 0.0f;

  for (int q = 0; q < NQ; ++q) {
    const int c = q >> 2, p = q & 3;
    __syncthreads();   // previous piece's MFMA reads done -> Bs free
    #pragma unroll
    for (int i = 0; i < 4; ++i) {
      int unit = i * 512 + tid;
      int r = unit >> 3, c16 = unit & 7;
      float4 lo = streg[2 * i], hi = streg[2 * i + 1];
      uint4 wv;
      wv.x = pkbf(lo.x, lo.y); wv.y = pkbf(lo.z, lo.w);
      wv.z = pkbf(hi.x, hi.y); wv.w = pkbf(hi.z, hi.w);
      *(uint4*)&u2.Bs[r][c16 * 8] = wv;
    }
    if (q + 1 < NQ) {
      const int cn = (q + 1) >> 2, pn = (q + 1) & 3;
      #pragma unroll
      for (int i = 0; i < 4; ++i) {
        int unit = i * 512 + tid;
        int r = unit >> 3, c16 = unit & 7;
        const float* src = Wenc + (size_t)(cn * BN + r) * DIN + pn * BK + c16 * 8;
        streg[2 * i]     = *(const float4*)src;
        streg[2 * i + 1] = *(const float4*)(src + 4);
      }
    }
    __syncthreads();   // Bs ready
    // B-fragments: B[n=lane&15][k=quad*8+j] from Bs[n][k] (B^T layout)
    #pragma unroll
    for (int nt = 0; nt < 2; ++nt) {
      #pragma unroll
      for (int kl = 0; kl < 2; ++kl) {
        bf16x8 bfrag = *(const bf16x8*)&u2.Bs[wave * 32 + nt * 16 + ln15][kl * 32 + quad * 8];
        acc[0][nt] = __builtin_amdgcn_mfma_f32_16x16x32_bf16(afrag[0][p * 2 + kl], bfrag, acc[0][nt], 0, 0, 0);
        acc[1][nt] = __builtin_amdgcn_mfma_f32_16x16x32_bf16(afrag[1][p * 2 + kl], bfrag, acc[1][nt], 0, 0, 0);
      }
    }
    if (p == 3) {
      // ---- chunk epilogue: +b_enc, relu, register sorted-list insert ----
      // C/D layout: col=lane&15, row=quad*4+reg (+16*mt)
      #pragma unroll
      for (int mt = 0; mt < 2; ++mt) {
        #pragma unroll
        for (int nt = 0; nt < 2; ++nt) {
          const int h  = c * BN + wave * 32 + nt * 16 + ln15;
          const float be = benc[h];
          const unsigned idxpart = (unsigned)(8191 - h);
          #pragma unroll
          for (int i = 0; i < 4; ++i) {
            const int s = mt * 4 + i;
            float v = acc[mt][nt][i] + be;
            acc[mt][nt][i] = 0.0f;
            v = v > 0.0f ? v : 0.0f;
            unsigned k = ((unsigned)f2bf(v) << 16) | idxpart;
            if (k > lst[s][LLEN - 1]) {     // beats my list's min -> insert
              #pragma unroll
              for (int j = 0; j < LLEN; ++j) {
                unsigned cur = lst[s][j];
                bool put = k > cur;
                lst[s][j] = put ? k : cur;
                k = put ? cur : k;
              }
            }
          }
        }
      }
    }
  }

  // ---- Stage 1: per-wave 16-lane shuffle tournament -> top-TW per row ----
  #pragma unroll
  for (int s = 0; s < 8; ++s) {
    const int row = (s >> 2) * 16 + quad * 4 + (s & 3);
    unsigned head = lst[s][0];
    for (int t = 0; t < TW; ++t) {
      unsigned m = head;
      #pragma unroll
      for (int d = 1; d < 16; d <<= 1) {
        unsigned o = __shfl_xor(m, d, 16);
        m = o > m ? o : m;
      }
      if (head == m) {        // I own the max (keys unique): pop + publish
        u1.mg[row][wave * TW + t] = m;
        #pragma unroll
        for (int j = 0; j < LLEN - 1; ++j) lst[s][j] = lst[s][j + 1];
        lst[s][LLEN - 1] = 0u;
      }
      head = lst[s][0];
    }
  }
  __syncthreads();

  // ---- Stage 2: exact rank-select top-64 of 192 per row (keys unique) ----
  {
    const int row = tid >> 4, lane16 = tid & 15;
    unsigned myk[12];
    int rank[12];
    #pragma unroll
    for (int j = 0; j < 12; ++j) {
      myk[j]  = u1.mg[row][lane16 + 16 * j];
      rank[j] = 0;
    }
    for (int e = 0; e < MG; ++e) {
      unsigned k2 = u1.mg[row][e];
      #pragma unroll
      for (int j = 0; j < 12; ++j) rank[j] += (k2 > myk[j]) ? 1 : 0;
    }
    #pragma unroll
    for (int j = 0; j < 12; ++j)
      if (rank[j] < NSEL) ti[row][rank[j]] = 8191 - (int)(myk[j] & 0xFFFFu);
  }

  // ---- stage exact f32 sae_in rows (overlays Bs; loop is done) ----
  {
    const int r = tid >> 4, seg = tid & 15;
    const float* xs = x + (size_t)(mb + r) * DIN + seg * 16;
    const float* bs = bdec + seg * 16;
    #pragma unroll
    for (int j = 0; j < 4; ++j) {
      float4 xv = *(const float4*)(xs + 4 * j);
      float4 bv = *(const float4*)(bs + 4 * j);
      float4 d;
      d.x = xv.x - bv.x; d.y = xv.y - bv.y; d.z = xv.z - bv.z; d.w = xv.w - bv.w;
      *(float4*)&u2.xf[r][seg * 16 + 4 * j] = d;
    }
  }
  __syncthreads();

  // ---- Phase 2: exact f64 re-rank of the 64 candidates per row ----
  {  // 2048 (row,cand) pairs; 4 threads per pair split K
    const int sub = tid & 3, pidx = tid >> 2;
    for (int j = 0; j < 16; ++j) {
      int pp = j * 128 + pidx;
      int row = pp >> 6, cand = pp & 63;
      int h = ti[row][cand];
      const float* wp = Wenc + (size_t)h * DIN + sub * 64;
      const float* xp = &u2.xf[row][sub * 64];
      double accd = 0.0;
      #pragma unroll
      for (int kk = 0; kk < 16; ++kk) {
        float4 w  = *(const float4*)(wp + 4 * kk);
        float4 xv = *(const float4*)(xp + 4 * kk);
        accd += (double)xv.x * (double)w.x;
        accd += (double)xv.y * (double)w.y;
        accd += (double)xv.z * (double)w.z;
        accd += (double)xv.w * (double)w.w;
      }
      accd += __shfl_down(accd, 2, 4);
      accd += __shfl_down(accd, 1, 4);
      if (sub == 0) {
        float ev = (float)accd + benc[h];
        ev = ev > 0.0f ? ev : 0.0f;   // relu before ranking (matches ref)
        tv[row][cand] = ev;
      }
    }
  }
  __syncthreads();
  if (tid < BM) {  // exact top-32 of 64 (value desc, idx asc — np top_k order)
    float* tvr = tv[tid];
    int*   tir = ti[tid];
    for (int s = 0; s < TOPK; ++s) {
      float bv = tvr[s]; int bi = tir[s]; int bp = s;
      for (int t2 = s + 1; t2 < NSEL; ++t2) {
        float v2 = tvr[t2]; int i2 = tir[t2];
        if (v2 > bv || (v2 == bv && (unsigned)i2 < (unsigned)bi)) {
          bv = v2; bi = i2; bp = t2;
        }
      }
      if (bp != s) {
        tvr[bp] = tvr[s]; tir[bp] = tir[s];
        tvr[s] = bv; tir[s] = bi;
      }
    }
  }
  __syncthreads();

  // ---- decode: out[b,:] = sum z_k * W_dec[idx_k,:] + b_dec  (all f32) ----
  {
    const int r = tid >> 4, seg = tid & 15, d0 = seg * 16;
    float od[16];
    #pragma unroll
    for (int j = 0; j < 4; ++j) {
      float4 b = *(const float4*)(bdec + d0 + 4 * j);
      od[4 * j] = b.x; od[4 * j + 1] = b.y; od[4 * j + 2] = b.z; od[4 * j + 3] = b.w;
    }
    for (int s = 0; s < TOPK; ++s) {
      float v = tv[r][s];
      if (!(v > 0.0f)) break;    // sorted desc
      int h = ti[r][s];
      const float* wp = Wdec + (size_t)h * DIN + d0;
      #pragma unroll
      for (int j = 0; j < 4; ++j) {
        float4 w = *(const float4*)(wp + 4 * j);
        od[4 * j]     += v * w.x;
        od[4 * j + 1] += v * w.y;
        od[4 * j + 2] += v * w.z;
        od[4 * j + 3] += v * w.w;
      }
    }
    float* op = out + (size_t)(mb + r) * DIN + d0;
    #pragma unroll
    for (int j = 0; j < 4; ++j) {
      float4 o;
      o.x = od[4 * j]; o.y = od[4 * j + 1]; o.z = od[4 * j + 2]; o.w = od[4 * j + 3];
      *(float4*)(op + 4 * j) = o;
    }
  }
}

extern "C" void kernel_launch(void* const* d_in, const int* in_sizes, int n_in,
                              void* d_out, int out_size, void* d_ws, size_t ws_size,
                              hipStream_t stream) {
  const float* x    = (const float*)d_in[0];
  const float* Wenc = (const float*)d_in[1];
  const float* benc = (const float*)d_in[2];
  const float* Wdec = (const float*)d_in[3];
  const float* bdec = (const float*)d_in[4];
  float* out = (float*)d_out;

  dim3 grid(BATCH / BM);   // 256 blocks, one per CU
  dim3 block(512);         // 8 waves
  sae_fused<<<grid, block, 0, stream>>>(x, Wenc, benc, Wdec, bdec, out);
}

// Round 9
// 538.331 us; speedup vs baseline: 8.7371x; 1.2903x over previous
//
#include <hip/hip_runtime.h>

#define DIN   256
#define HID   8192
#define BATCH 8192
#define TOPK  32
#define NSEL  64          // superset size for exact re-rank
#define BM    32
#define BN    256
#define BK    64
#define NC    32          // chunk-cols (HID/BN)
#define AS_LD 264         // 528 B row stride
#define BS_LD 72          // 144 B row stride
#define XF_LD 260
#define TW    24          // tournament pops per wave per row
#define MG    (8*TW)      // 192 merged candidates per row
#define MG_LD 193
#define LLEN  8           // per-(thread,row) register list length

typedef __bf16 bf16x8 __attribute__((ext_vector_type(8)));
typedef float f32x4v __attribute__((ext_vector_type(4)));

__device__ __forceinline__ unsigned short f2bf(float f) {
  unsigned x = __builtin_bit_cast(unsigned, f);
  x = x + 0x7fffu + ((x >> 16) & 1u);   // RNE, finite only
  return (unsigned short)(x >> 16);
}
__device__ __forceinline__ unsigned pkbf(float a, float b) {
  return (unsigned)f2bf(a) | ((unsigned)f2bf(b) << 16);
}

union U1 { unsigned short As[BM][AS_LD]; unsigned mg[BM][MG_LD]; };  // 24.7 KB
union U2 { unsigned short Bs[BN][BS_LD]; float xf[BM][XF_LD]; };     // 36.9 KB

// SPILL ROOT-CAUSE (r8): afrag was indexed by runtime p (q&3) -> SROA cannot
// promote a dynamically-indexed private array -> afrag lived in SCRATCH
// (256 B/thread == the exact 32 MiB excess WRITE_SIZE; 128 KB/CU working set
// == 4 MB/XCD == L2 capacity -> thrash -> 77% stall). No launch-bounds /
// waves_per_eu attribute can fix an alloca. Fix: unroll p so all afrag
// indices are compile-time. lst/streg/acc were always statically indexed.
__global__ __launch_bounds__(512) __attribute__((amdgpu_waves_per_eu(2, 2)))
void sae_fused(
    const float* __restrict__ x,    const float* __restrict__ Wenc,
    const float* __restrict__ benc, const float* __restrict__ Wdec,
    const float* __restrict__ bdec, float* __restrict__ out)
{
  __shared__ __align__(16) U1 u1;
  __shared__ __align__(16) U2 u2;
  __shared__ float tv[BM][NSEL];
  __shared__ int   ti[BM][NSEL];

  const int tid  = (int)threadIdx.x;
  const int wave = tid >> 6;
  const int lane = tid & 63;
  const int quad = lane >> 4;
  const int ln15 = lane & 15;
  const int mb   = (int)blockIdx.x * BM;

  // ---- Phase 0: stage bf16(x - b_dec) rows into LDS ----
  {
    const int r = tid >> 4, seg = tid & 15;
    const float* xs = x + (size_t)(mb + r) * DIN + seg * 16;
    const float* bs = bdec + seg * 16;
    #pragma unroll
    for (int j = 0; j < 4; ++j) {
      float4 xv = *(const float4*)(xs + 4 * j);
      float4 bv = *(const float4*)(bs + 4 * j);
      unsigned short* dst = &u1.As[r][seg * 16 + 4 * j];
      dst[0] = f2bf(xv.x - bv.x); dst[1] = f2bf(xv.y - bv.y);
      dst[2] = f2bf(xv.z - bv.z); dst[3] = f2bf(xv.w - bv.w);
    }
  }
  __syncthreads();

  // A-fragments (verified 16x16x32 layout): A[m=lane&15][k=quad*8+j]
  bf16x8 afrag[2][8];
  #pragma unroll
  for (int mt = 0; mt < 2; ++mt)
    #pragma unroll
    for (int gk = 0; gk < 8; ++gk)
      afrag[mt][gk] = *(const bf16x8*)&u1.As[mt * 16 + ln15][gk * 32 + quad * 8];
  __syncthreads();

  // ---- private top-LLEN key lists, one per owned row (slot s = mt*4+i) ----
  // key = (bf16(v)<<16) | (8191-h): u32 order == (value desc, idx asc)
  unsigned lst[8][LLEN];
  #pragma unroll
  for (int s = 0; s < 8; ++s)
    #pragma unroll
    for (int j = 0; j < LLEN; ++j) lst[s][j] = 0u;

  // ---- software-pipelined W_enc staging (f32 load -> bf16 LDS) ----
  const int sr = tid >> 3, sc16 = tid & 7;           // staging row/col16 for i=0
  float4 streg[8];
  #pragma unroll
  for (int i = 0; i < 4; ++i) {
    const float* src = Wenc + (size_t)(sr + i * 64) * DIN + sc16 * 8;  // piece 0
    streg[2 * i]     = *(const float4*)src;
    streg[2 * i + 1] = *(const float4*)(src + 4);
  }

  f32x4v acc[2][2];
  #pragma unroll
  for (int mt = 0; mt < 2; ++mt)
    #pragma unroll
    for (int nt = 0; nt < 2; ++nt)
      #pragma unroll
      for (int i = 0; i < 4; ++i) acc[mt][nt][i] = 0.0f;

  for (int c = 0; c < NC; ++c) {
    #pragma unroll
    for (int p = 0; p < 4; ++p) {            // p compile-time -> afrag static
      __syncthreads();   // previous piece's MFMA reads done -> Bs free
      #pragma unroll
      for (int i = 0; i < 4; ++i) {
        float4 lo = streg[2 * i], hi = streg[2 * i + 1];
        uint4 wv;
        wv.x = pkbf(lo.x, lo.y); wv.y = pkbf(lo.z, lo.w);
        wv.z = pkbf(hi.x, hi.y); wv.w = pkbf(hi.z, hi.w);
        *(uint4*)&u2.Bs[sr + i * 64][sc16 * 8] = wv;
      }
      {
        const int nxt = c * 4 + p + 1;
        if (nxt < NC * 4) {
          const int cn = nxt >> 2, pn = nxt & 3;
          const float* base = Wenc + (size_t)(cn * BN + sr) * DIN + pn * BK + sc16 * 8;
          #pragma unroll
          for (int i = 0; i < 4; ++i) {
            const float* src = base + (size_t)(i * 64) * DIN;
            streg[2 * i]     = *(const float4*)src;
            streg[2 * i + 1] = *(const float4*)(src + 4);
          }
        }
      }
      __syncthreads();   // Bs ready
      // B-fragments: B[n=lane&15][k=quad*8+j] from Bs[n][k] (B^T layout)
      #pragma unroll
      for (int nt = 0; nt < 2; ++nt) {
        #pragma unroll
        for (int kl = 0; kl < 2; ++kl) {
          bf16x8 bfrag = *(const bf16x8*)&u2.Bs[wave * 32 + nt * 16 + ln15][kl * 32 + quad * 8];
          acc[0][nt] = __builtin_amdgcn_mfma_f32_16x16x32_bf16(afrag[0][p * 2 + kl], bfrag, acc[0][nt], 0, 0, 0);
          acc[1][nt] = __builtin_amdgcn_mfma_f32_16x16x32_bf16(afrag[1][p * 2 + kl], bfrag, acc[1][nt], 0, 0, 0);
        }
      }
    }
    // ---- chunk epilogue: +b_enc, relu, register sorted-list insert ----
    // C/D layout: col=lane&15, row=quad*4+reg (+16*mt)
    #pragma unroll
    for (int mt = 0; mt < 2; ++mt) {
      #pragma unroll
      for (int nt = 0; nt < 2; ++nt) {
        const int h  = c * BN + wave * 32 + nt * 16 + ln15;
        const float be = benc[h];
        const unsigned idxpart = (unsigned)(8191 - h);
        #pragma unroll
        for (int i = 0; i < 4; ++i) {
          const int s = mt * 4 + i;
          float v = acc[mt][nt][i] + be;
          acc[mt][nt][i] = 0.0f;
          v = v > 0.0f ? v : 0.0f;
          unsigned k = ((unsigned)f2bf(v) << 16) | idxpart;
          if (k > lst[s][LLEN - 1]) {     // beats my list's min -> insert
            #pragma unroll
            for (int j = 0; j < LLEN; ++j) {
              unsigned cur = lst[s][j];
              bool put = k > cur;
              lst[s][j] = put ? k : cur;
              k = put ? cur : k;
            }
          }
        }
      }
    }
  }

  // ---- Stage 1: per-wave 16-lane shuffle tournament -> top-TW per row ----
  #pragma unroll
  for (int s = 0; s < 8; ++s) {
    const int row = (s >> 2) * 16 + quad * 4 + (s & 3);
    unsigned head = lst[s][0];
    for (int t = 0; t < TW; ++t) {
      unsigned m = head;
      #pragma unroll
      for (int d = 1; d < 16; d <<= 1) {
        unsigned o = __shfl_xor(m, d, 16);
        m = o > m ? o : m;
      }
      if (head == m) {        // I own the max (keys unique): pop + publish
        u1.mg[row][wave * TW + t] = m;
        #pragma unroll
        for (int j = 0; j < LLEN - 1; ++j) lst[s][j] = lst[s][j + 1];
        lst[s][LLEN - 1] = 0u;
      }
      head = lst[s][0];
    }
  }
  __syncthreads();

  // ---- Stage 2: exact rank-select top-64 of 192 per row (keys unique) ----
  {
    const int row = tid >> 4, lane16 = tid & 15;
    unsigned myk[12];
    int rank[12];
    #pragma unroll
    for (int j = 0; j < 12; ++j) {
      myk[j]  = u1.mg[row][lane16 + 16 * j];
      rank[j] = 0;
    }
    for (int e = 0; e < MG; ++e) {
      unsigned k2 = u1.mg[row][e];
      #pragma unroll
      for (int j = 0; j < 12; ++j) rank[j] += (k2 > myk[j]) ? 1 : 0;
    }
    #pragma unroll
    for (int j = 0; j < 12; ++j)
      if (rank[j] < NSEL) ti[row][rank[j]] = 8191 - (int)(myk[j] & 0xFFFFu);
  }

  // ---- stage exact f32 sae_in rows (overlays Bs; loop is done) ----
  {
    const int r = tid >> 4, seg = tid & 15;
    const float* xs = x + (size_t)(mb + r) * DIN + seg * 16;
    const float* bs = bdec + seg * 16;
    #pragma unroll
    for (int j = 0; j < 4; ++j) {
      float4 xv = *(const float4*)(xs + 4 * j);
      float4 bv = *(const float4*)(bs + 4 * j);
      float4 d;
      d.x = xv.x - bv.x; d.y = xv.y - bv.y; d.z = xv.z - bv.z; d.w = xv.w - bv.w;
      *(float4*)&u2.xf[r][seg * 16 + 4 * j] = d;
    }
  }
  __syncthreads();

  // ---- Phase 2: exact f64 re-rank of the 64 candidates per row ----
  {  // 2048 (row,cand) pairs; 4 threads per pair split K
    const int sub = tid & 3, pidx = tid >> 2;
    for (int j = 0; j < 16; ++j) {
      int pp = j * 128 + pidx;
      int row = pp >> 6, cand = pp & 63;
      int h = ti[row][cand];
      const float* wp = Wenc + (size_t)h * DIN + sub * 64;
      const float* xp = &u2.xf[row][sub * 64];
      double accd = 0.0;
      #pragma unroll
      for (int kk = 0; kk < 16; ++kk) {
        float4 w  = *(const float4*)(wp + 4 * kk);
        float4 xv = *(const float4*)(xp + 4 * kk);
        accd += (double)xv.x * (double)w.x;
        accd += (double)xv.y * (double)w.y;
        accd += (double)xv.z * (double)w.z;
        accd += (double)xv.w * (double)w.w;
      }
      accd += __shfl_down(accd, 2, 4);
      accd += __shfl_down(accd, 1, 4);
      if (sub == 0) {
        float ev = (float)accd + benc[h];
        ev = ev > 0.0f ? ev : 0.0f;   // relu before ranking (matches ref)
        tv[row][cand] = ev;
      }
    }
  }
  __syncthreads();
  if (tid < BM) {  // exact top-32 of 64 (value desc, idx asc — np top_k order)
    float* tvr = tv[tid];
    int*   tir = ti[tid];
    for (int s = 0; s < TOPK; ++s) {
      float bv = tvr[s]; int bi = tir[s]; int bp = s;
      for (int t2 = s + 1; t2 < NSEL; ++t2) {
        float v2 = tvr[t2]; int i2 = tir[t2];
        if (v2 > bv || (v2 == bv && (unsigned)i2 < (unsigned)bi)) {
          bv = v2; bi = i2; bp = t2;
        }
      }
      if (bp != s) {
        tvr[bp] = tvr[s]; tir[bp] = tir[s];
        tvr[s] = bv; tir[s] = bi;
      }
    }
  }
  __syncthreads();

  // ---- decode: out[b,:] = sum z_k * W_dec[idx_k,:] + b_dec  (all f32) ----
  {
    const int r = tid >> 4, seg = tid & 15, d0 = seg * 16;
    float od[16];
    #pragma unroll
    for (int j = 0; j < 4; ++j) {
      float4 b = *(const float4*)(bdec + d0 + 4 * j);
      od[4 * j] = b.x; od[4 * j + 1] = b.y; od[4 * j + 2] = b.z; od[4 * j + 3] = b.w;
    }
    for (int s = 0; s < TOPK; ++s) {
      float v = tv[r][s];
      if (!(v > 0.0f)) break;    // sorted desc
      int h = ti[r][s];
      const float* wp = Wdec + (size_t)h * DIN + d0;
      #pragma unroll
      for (int j = 0; j < 4; ++j) {
        float4 w = *(const float4*)(wp + 4 * j);
        od[4 * j]     += v * w.x;
        od[4 * j + 1] += v * w.y;
        od[4 * j + 2] += v * w.z;
        od[4 * j + 3] += v * w.w;
      }
    }
    float* op = out + (size_t)(mb + r) * DIN + d0;
    #pragma unroll
    for (int j = 0; j < 4; ++j) {
      float4 o;
      o.x = od[4 * j]; o.y = od[4 * j + 1]; o.z = od[4 * j + 2]; o.w = od[4 * j + 3];
      *(float4*)(op + 4 * j) = o;
    }
  }
}

extern "C" void kernel_launch(void* const* d_in, const int* in_sizes, int n_in,
                              void* d_out, int out_size, void* d_ws, size_t ws_size,
                              hipStream_t stream) {
  const float* x    = (const float*)d_in[0];
  const float* Wenc = (const float*)d_in[1];
  const float* benc = (const float*)d_in[2];
  const float* Wdec = (const float*)d_in[3];
  const float* bdec = (const float*)d_in[4];
  float* out = (float*)d_out;

  dim3 grid(BATCH / BM);   // 256 blocks, one per CU
  dim3 block(512);         // 8 waves
  sae_fused<<<grid, block, 0, stream>>>(x, Wenc, benc, Wdec, bdec, out);
}

// Round 10
// 481.443 us; speedup vs baseline: 9.7695x; 1.1182x over previous
//
#include <hip/hip_runtime.h>

#define DIN   256
#define HID   8192
#define BATCH 8192
#define TOPK  32
#define NSEL  64          // superset size for exact re-rank
#define BM    32
#define BN    256
#define NC    32          // hid chunks (HID/BN)
#define AS_LD 264         // 528 B row stride
#define XF_LD 260
#define TW    24          // tournament pops per wave per row
#define MG    (8*TW)      // 192 merged candidates per row
#define MG_LD 193
#define LLEN  8           // per-(thread,row) register list depth

typedef __bf16 bf16x8 __attribute__((ext_vector_type(8)));
typedef unsigned short u16x8 __attribute__((ext_vector_type(8)));
typedef float f32x4v __attribute__((ext_vector_type(4)));

__device__ __forceinline__ unsigned short f2bf(float f) {
  unsigned x = __builtin_bit_cast(unsigned, f);
  x = x + 0x7fffu + ((x >> 16) & 1u);   // RNE, finite only
  return (unsigned short)(x >> 16);
}

// ---------------- Kernel A: W_enc f32 -> bf16, MFMA-B-fragment layout ----
// ws[ ((h>>4)*8 + kg)*64 + quad*16 + (h&15) ] : u16x8 = Wenc[h][kg*32+quad*8 ..+7]
// so kernel B's wave reads fragment (tile,kg) at lane-contiguous 16B: 1KB/wave.
__global__ __launch_bounds__(512) void wenc_cast(
    const float* __restrict__ Wenc, unsigned short* __restrict__ wsb)
{
  const int g = (int)blockIdx.x * 512 + (int)threadIdx.x;  // 262144 units
  const int h = g >> 5, u = g & 31, kg = u >> 2, quad = u & 3;
  const float* src = Wenc + (size_t)h * DIN + kg * 32 + quad * 8;
  float4 a = *(const float4*)src;
  float4 b = *(const float4*)(src + 4);
  u16x8 o;
  o[0] = f2bf(a.x); o[1] = f2bf(a.y); o[2] = f2bf(a.z); o[3] = f2bf(a.w);
  o[4] = f2bf(b.x); o[5] = f2bf(b.y); o[6] = f2bf(b.z); o[7] = f2bf(b.w);
  *(u16x8*)(wsb + ((size_t)(((h >> 4) * 8 + kg) * 64 + quad * 16 + (h & 15))) * 8) = o;
}

union U1 { unsigned short As[BM][AS_LD]; unsigned mg[BM][MG_LD]; };  // 24.7 KB

// LLC-BW root-cause (r9): 256 blocks x 8.39MB f32 W_enc = 2.15GB at exactly
// the measured 4.0 TB/s LLC rate. bf16 fragment-precast (kernel A) halves
// bytes AND fits the 4MB per-XCD L2; B loads go straight from global
// (no LDS staging, no K-loop barriers, no 8-way-conflict ds_reads).
__global__ __launch_bounds__(512) __attribute__((amdgpu_waves_per_eu(2, 2)))
void sae_fused(
    const float* __restrict__ x,    const float* __restrict__ Wenc,
    const float* __restrict__ benc, const float* __restrict__ Wdec,
    const float* __restrict__ bdec, const unsigned short* __restrict__ wsb,
    float* __restrict__ out)
{
  __shared__ __align__(16) U1 u1;
  __shared__ __align__(16) float xf[BM][XF_LD];
  __shared__ float tv[BM][NSEL];
  __shared__ int   ti[BM][NSEL];

  const int tid  = (int)threadIdx.x;
  const int wave = tid >> 6;
  const int lane = tid & 63;
  const int quad = lane >> 4;
  const int ln15 = lane & 15;
  const int mb   = (int)blockIdx.x * BM;

  // ---- Phase 0: stage bf16(x - b_dec) rows into LDS ----
  {
    const int r = tid >> 4, seg = tid & 15;
    const float* xs = x + (size_t)(mb + r) * DIN + seg * 16;
    const float* bs = bdec + seg * 16;
    #pragma unroll
    for (int j = 0; j < 4; ++j) {
      float4 xv = *(const float4*)(xs + 4 * j);
      float4 bv = *(const float4*)(bs + 4 * j);
      unsigned short* dst = &u1.As[r][seg * 16 + 4 * j];
      dst[0] = f2bf(xv.x - bv.x); dst[1] = f2bf(xv.y - bv.y);
      dst[2] = f2bf(xv.z - bv.z); dst[3] = f2bf(xv.w - bv.w);
    }
  }
  __syncthreads();

  // A-fragments (verified 16x16x32 layout): A[m=lane&15][k=quad*8+j]
  bf16x8 afrag[2][8];
  #pragma unroll
  for (int mt = 0; mt < 2; ++mt)
    #pragma unroll
    for (int gk = 0; gk < 8; ++gk)
      afrag[mt][gk] = *(const bf16x8*)&u1.As[mt * 16 + ln15][gk * 32 + quad * 8];
  __syncthreads();   // all afrag reads done before mg overlays As

  // ---- private top-LLEN key lists, one per owned row (slot s = mt*4+i) ----
  // key = (bf16(v)<<16) | (8191-h): u32 order == (value desc, idx asc)
  unsigned lst[8][LLEN];
  #pragma unroll
  for (int s = 0; s < 8; ++s)
    #pragma unroll
    for (int j = 0; j < LLEN; ++j) lst[s][j] = 0u;

  f32x4v acc[2][2];
  #pragma unroll
  for (int mt = 0; mt < 2; ++mt)
    #pragma unroll
    for (int nt = 0; nt < 2; ++nt)
      #pragma unroll
      for (int i = 0; i < 4; ++i) acc[mt][nt][i] = 0.0f;

  // ---- K-loop: barrier-free, B-fragments straight from global bf16 ----
  for (int c = 0; c < NC; ++c) {
    #pragma unroll
    for (int nt = 0; nt < 2; ++nt) {
      const int tile = c * 16 + wave * 2 + nt;
      const unsigned short* bp = wsb + ((size_t)tile * 8 * 64 + lane) * 8;
      bf16x8 bfrag[8];
      #pragma unroll
      for (int kg = 0; kg < 8; ++kg)
        bfrag[kg] = *(const bf16x8*)(bp + (size_t)kg * 64 * 8);
      #pragma unroll
      for (int kg = 0; kg < 8; ++kg) {
        acc[0][nt] = __builtin_amdgcn_mfma_f32_16x16x32_bf16(afrag[0][kg], bfrag[kg], acc[0][nt], 0, 0, 0);
        acc[1][nt] = __builtin_amdgcn_mfma_f32_16x16x32_bf16(afrag[1][kg], bfrag[kg], acc[1][nt], 0, 0, 0);
      }
    }
    // ---- chunk epilogue: +b_enc, relu, register sorted-list insert ----
    // C/D layout: col=lane&15, row=quad*4+reg (+16*mt)
    #pragma unroll
    for (int mt = 0; mt < 2; ++mt) {
      #pragma unroll
      for (int nt = 0; nt < 2; ++nt) {
        const int h  = c * BN + wave * 32 + nt * 16 + ln15;
        const float be = benc[h];
        const unsigned idxpart = (unsigned)(8191 - h);
        #pragma unroll
        for (int i = 0; i < 4; ++i) {
          const int s = mt * 4 + i;
          float v = acc[mt][nt][i] + be;
          acc[mt][nt][i] = 0.0f;
          v = v > 0.0f ? v : 0.0f;
          unsigned k = ((unsigned)f2bf(v) << 16) | idxpart;
          if (k > lst[s][LLEN - 1]) {     // beats my list's min -> insert
            #pragma unroll
            for (int j = 0; j < LLEN; ++j) {
              unsigned cur = lst[s][j];
              bool put = k > cur;
              lst[s][j] = put ? k : cur;
              k = put ? cur : k;
            }
          }
        }
      }
    }
  }

  // ---- Stage 1: per-wave 16-lane shuffle tournament -> top-TW per row ----
  #pragma unroll
  for (int s = 0; s < 8; ++s) {
    const int row = (s >> 2) * 16 + quad * 4 + (s & 3);
    unsigned head = lst[s][0];
    for (int t = 0; t < TW; ++t) {
      unsigned m = head;
      #pragma unroll
      for (int d = 1; d < 16; d <<= 1) {
        unsigned o = __shfl_xor(m, d, 16);
        m = o > m ? o : m;
      }
      if (head == m) {        // I own the max (keys unique): pop + publish
        u1.mg[row][wave * TW + t] = m;
        #pragma unroll
        for (int j = 0; j < LLEN - 1; ++j) lst[s][j] = lst[s][j + 1];
        lst[s][LLEN - 1] = 0u;
      }
      head = lst[s][0];
    }
  }
  __syncthreads();

  // ---- Stage 2: exact rank-select top-64 of 192 per row (keys unique) ----
  {
    const int row = tid >> 4, lane16 = tid & 15;
    unsigned myk[12];
    int rank[12];
    #pragma unroll
    for (int j = 0; j < 12; ++j) {
      myk[j]  = u1.mg[row][lane16 + 16 * j];
      rank[j] = 0;
    }
    for (int e = 0; e < MG; ++e) {
      unsigned k2 = u1.mg[row][e];
      #pragma unroll
      for (int j = 0; j < 12; ++j) rank[j] += (k2 > myk[j]) ? 1 : 0;
    }
    #pragma unroll
    for (int j = 0; j < 12; ++j)
      if (rank[j] < NSEL) ti[row][rank[j]] = 8191 - (int)(myk[j] & 0xFFFFu);
  }

  // ---- stage exact f32 sae_in rows ----
  {
    const int r = tid >> 4, seg = tid & 15;
    const float* xs = x + (size_t)(mb + r) * DIN + seg * 16;
    const float* bs = bdec + seg * 16;
    #pragma unroll
    for (int j = 0; j < 4; ++j) {
      float4 xv = *(const float4*)(xs + 4 * j);
      float4 bv = *(const float4*)(bs + 4 * j);
      float4 d;
      d.x = xv.x - bv.x; d.y = xv.y - bv.y; d.z = xv.z - bv.z; d.w = xv.w - bv.w;
      *(float4*)&xf[r][seg * 16 + 4 * j] = d;
    }
  }
  __syncthreads();

  // ---- Phase 2: exact f64 re-rank of the 64 candidates per row ----
  {  // 2048 (row,cand) pairs; 4 threads per pair split K
    const int sub = tid & 3, pidx = tid >> 2;
    for (int j = 0; j < 16; ++j) {
      int pp = j * 128 + pidx;
      int row = pp >> 6, cand = pp & 63;
      int h = ti[row][cand];
      const float* wp = Wenc + (size_t)h * DIN + sub * 64;
      const float* xp = &xf[row][sub * 64];
      double accd = 0.0;
      #pragma unroll
      for (int kk = 0; kk < 16; ++kk) {
        float4 w  = *(const float4*)(wp + 4 * kk);
        float4 xv = *(const float4*)(xp + 4 * kk);
        accd += (double)xv.x * (double)w.x;
        accd += (double)xv.y * (double)w.y;
        accd += (double)xv.z * (double)w.z;
        accd += (double)xv.w * (double)w.w;
      }
      accd += __shfl_down(accd, 2, 4);
      accd += __shfl_down(accd, 1, 4);
      if (sub == 0) {
        float ev = (float)accd + benc[h];
        ev = ev > 0.0f ? ev : 0.0f;   // relu before ranking (matches ref)
        tv[row][cand] = ev;
      }
    }
  }
  __syncthreads();
  if (tid < BM) {  // exact top-32 of 64 (value desc, idx asc — np top_k order)
    float* tvr = tv[tid];
    int*   tir = ti[tid];
    for (int s = 0; s < TOPK; ++s) {
      float bv = tvr[s]; int bi = tir[s]; int bp = s;
      for (int t2 = s + 1; t2 < NSEL; ++t2) {
        float v2 = tvr[t2]; int i2 = tir[t2];
        if (v2 > bv || (v2 == bv && (unsigned)i2 < (unsigned)bi)) {
          bv = v2; bi = i2; bp = t2;
        }
      }
      if (bp != s) {
        tvr[bp] = tvr[s]; tir[bp] = tir[s];
        tvr[s] = bv; tir[s] = bi;
      }
    }
  }
  __syncthreads();

  // ---- decode: out[b,:] = sum z_k * W_dec[idx_k,:] + b_dec  (all f32) ----
  {
    const int r = tid >> 4, seg = tid & 15, d0 = seg * 16;
    float od[16];
    #pragma unroll
    for (int j = 0; j < 4; ++j) {
      float4 b = *(const float4*)(bdec + d0 + 4 * j);
      od[4 * j] = b.x; od[4 * j + 1] = b.y; od[4 * j + 2] = b.z; od[4 * j + 3] = b.w;
    }
    for (int s = 0; s < TOPK; ++s) {
      float v = tv[r][s];
      if (!(v > 0.0f)) break;    // sorted desc
      int h = ti[r][s];
      const float* wp = Wdec + (size_t)h * DIN + d0;
      #pragma unroll
      for (int j = 0; j < 4; ++j) {
        float4 w = *(const float4*)(wp + 4 * j);
        od[4 * j]     += v * w.x;
        od[4 * j + 1] += v * w.y;
        od[4 * j + 2] += v * w.z;
        od[4 * j + 3] += v * w.w;
      }
    }
    float* op = out + (size_t)(mb + r) * DIN + d0;
    #pragma unroll
    for (int j = 0; j < 4; ++j) {
      float4 o;
      o.x = od[4 * j]; o.y = od[4 * j + 1]; o.z = od[4 * j + 2]; o.w = od[4 * j + 3];
      *(float4*)(op + 4 * j) = o;
    }
  }
}

extern "C" void kernel_launch(void* const* d_in, const int* in_sizes, int n_in,
                              void* d_out, int out_size, void* d_ws, size_t ws_size,
                              hipStream_t stream) {
  const float* x    = (const float*)d_in[0];
  const float* Wenc = (const float*)d_in[1];
  const float* benc = (const float*)d_in[2];
  const float* Wdec = (const float*)d_in[3];
  const float* bdec = (const float*)d_in[4];
  float* out = (float*)d_out;
  unsigned short* wsb = (unsigned short*)d_ws;   // 4 MiB bf16 fragment image

  wenc_cast<<<dim3((HID * DIN / 8) / 512), dim3(512), 0, stream>>>(Wenc, wsb);
  sae_fused<<<dim3(BATCH / BM), dim3(512), 0, stream>>>(x, Wenc, benc, Wdec, bdec, wsb, out);
}

// Round 11
// 436.168 us; speedup vs baseline: 10.7836x; 1.1038x over previous
//
#include <hip/hip_runtime.h>

#define DIN   256
#define HID   8192
#define BATCH 8192
#define TOPK  32
#define BM    32
#define HHALF 4096
#define NCH   16          // hid chunks per half (256 latents each)
#define NS1   48          // per-half approx top-k kept
#define MRG   96          // merged candidates per row
#define NS2   48          // exact-rerank count
#define AS_LD 264         // 528 B row stride
#define XF_LD 260
#define TW    24          // tournament pops per wave per row
#define MG    (8*TW)      // 192 merged per row per half
#define MG_LD 193
#define LLEN  8           // per-(thread,row) register list depth
#define GK_OFF ((size_t)4 << 20)   // key buffer offset in ws (after 4MiB wsb)

typedef __bf16 bf16x8 __attribute__((ext_vector_type(8)));
typedef unsigned short u16x8 __attribute__((ext_vector_type(8)));
typedef float f32x4v __attribute__((ext_vector_type(4)));

__device__ __forceinline__ unsigned short f2bf(float f) {
  unsigned x = __builtin_bit_cast(unsigned, f);
  x = x + 0x7fffu + ((x >> 16) & 1u);   // RNE, finite only
  return (unsigned short)(x >> 16);
}

// ---------------- Kernel A: W_enc f32 -> bf16, MFMA-B-fragment layout ----
__global__ __launch_bounds__(512) void wenc_cast(
    const float* __restrict__ Wenc, unsigned short* __restrict__ wsb)
{
  const int g = (int)blockIdx.x * 512 + (int)threadIdx.x;  // 262144 units
  const int h = g >> 5, u = g & 31, kg = u >> 2, quad = u & 3;
  const float* src = Wenc + (size_t)h * DIN + kg * 32 + quad * 8;
  float4 a = *(const float4*)src;
  float4 b = *(const float4*)(src + 4);
  u16x8 o;
  o[0] = f2bf(a.x); o[1] = f2bf(a.y); o[2] = f2bf(a.z); o[3] = f2bf(a.w);
  o[4] = f2bf(b.x); o[5] = f2bf(b.y); o[6] = f2bf(b.z); o[7] = f2bf(b.w);
  *(u16x8*)(wsb + ((size_t)(((h >> 4) * 8 + kg) * 64 + quad * 16 + (h & 15))) * 8) = o;
}

union U1 { unsigned short As[BM][AS_LD]; unsigned mg[BM][MG_LD]; };  // 24.7 KB

// ---------------- Kernel B1: encoder GEMM + per-half approx top-48 ----
// grid 512: rowtile rt = blockIdx>>1 (32 rows), half hs = blockIdx&1.
// XCD = blockIdx%8 (round-robin) => all blocks on one XCD share hs ->
// their 2MB wsb half stays L2-resident (r10 was LLC-BW-bound at 4.5 TB/s
// streaming 256x4MB through the LLC).
__global__ __launch_bounds__(512) __attribute__((amdgpu_waves_per_eu(2, 2)))
void sae_enc(
    const float* __restrict__ x,    const float* __restrict__ benc,
    const float* __restrict__ bdec, const unsigned short* __restrict__ wsb,
    unsigned* __restrict__ gkeys)
{
  __shared__ __align__(16) U1 u1;

  const int tid  = (int)threadIdx.x;
  const int wave = tid >> 6;
  const int lane = tid & 63;
  const int quad = lane >> 4;
  const int ln15 = lane & 15;
  const int rt   = (int)blockIdx.x >> 1;
  const int hs   = (int)blockIdx.x & 1;
  const int mb   = rt * BM;

  // ---- stage bf16(x - b_dec) rows into LDS ----
  {
    const int r = tid >> 4, seg = tid & 15;
    const float* xs = x + (size_t)(mb + r) * DIN + seg * 16;
    const float* bs = bdec + seg * 16;
    #pragma unroll
    for (int j = 0; j < 4; ++j) {
      float4 xv = *(const float4*)(xs + 4 * j);
      float4 bv = *(const float4*)(bs + 4 * j);
      unsigned short* dst = &u1.As[r][seg * 16 + 4 * j];
      dst[0] = f2bf(xv.x - bv.x); dst[1] = f2bf(xv.y - bv.y);
      dst[2] = f2bf(xv.z - bv.z); dst[3] = f2bf(xv.w - bv.w);
    }
  }
  __syncthreads();

  // A-fragments (verified 16x16x32 layout): A[m=lane&15][k=quad*8+j]
  bf16x8 afrag[2][8];
  #pragma unroll
  for (int mt = 0; mt < 2; ++mt)
    #pragma unroll
    for (int gk = 0; gk < 8; ++gk)
      afrag[mt][gk] = *(const bf16x8*)&u1.As[mt * 16 + ln15][gk * 32 + quad * 8];
  __syncthreads();   // afrag reads done before mg overlays As

  // key = (bf16(v)<<16) | (8191-h): u32 order == (value desc, idx asc); unique.
  unsigned lst[8][LLEN];
  #pragma unroll
  for (int s = 0; s < 8; ++s)
    #pragma unroll
    for (int j = 0; j < LLEN; ++j) lst[s][j] = 0u;

  f32x4v acc[2][2];
  #pragma unroll
  for (int mt = 0; mt < 2; ++mt)
    #pragma unroll
    for (int nt = 0; nt < 2; ++nt)
      #pragma unroll
      for (int i = 0; i < 4; ++i) acc[mt][nt][i] = 0.0f;

  for (int c = 0; c < NCH; ++c) {
    #pragma unroll
    for (int nt = 0; nt < 2; ++nt) {
      const int tile = hs * 256 + c * 16 + wave * 2 + nt;
      const unsigned short* bp = wsb + ((size_t)tile * 512 + lane) * 8;
      bf16x8 bfrag[8];
      #pragma unroll
      for (int kg = 0; kg < 8; ++kg)
        bfrag[kg] = *(const bf16x8*)(bp + (size_t)kg * 512);
      #pragma unroll
      for (int kg = 0; kg < 8; ++kg) {
        acc[0][nt] = __builtin_amdgcn_mfma_f32_16x16x32_bf16(afrag[0][kg], bfrag[kg], acc[0][nt], 0, 0, 0);
        acc[1][nt] = __builtin_amdgcn_mfma_f32_16x16x32_bf16(afrag[1][kg], bfrag[kg], acc[1][nt], 0, 0, 0);
      }
    }
    // epilogue: +b_enc, relu, register sorted-list insert
    #pragma unroll
    for (int mt = 0; mt < 2; ++mt) {
      #pragma unroll
      for (int nt = 0; nt < 2; ++nt) {
        const int h  = hs * HHALF + c * 256 + wave * 32 + nt * 16 + ln15;
        const float be = benc[h];
        const unsigned idxpart = (unsigned)(8191 - h);
        #pragma unroll
        for (int i = 0; i < 4; ++i) {
          const int s = mt * 4 + i;
          float v = acc[mt][nt][i] + be;
          acc[mt][nt][i] = 0.0f;
          v = v > 0.0f ? v : 0.0f;
          unsigned k = ((unsigned)f2bf(v) << 16) | idxpart;
          if (k > lst[s][LLEN - 1]) {
            #pragma unroll
            for (int j = 0; j < LLEN; ++j) {
              unsigned cur = lst[s][j];
              bool put = k > cur;
              lst[s][j] = put ? k : cur;
              k = put ? cur : k;
            }
          }
        }
      }
    }
  }

  // per-wave 16-lane tournament -> top-TW per row per wave
  #pragma unroll
  for (int s = 0; s < 8; ++s) {
    const int row = (s >> 2) * 16 + quad * 4 + (s & 3);
    unsigned head = lst[s][0];
    for (int t = 0; t < TW; ++t) {
      unsigned m = head;
      #pragma unroll
      for (int d = 1; d < 16; d <<= 1) {
        unsigned o = __shfl_xor(m, d, 16);
        m = o > m ? o : m;
      }
      if (head == m) {
        u1.mg[row][wave * TW + t] = m;
        #pragma unroll
        for (int j = 0; j < LLEN - 1; ++j) lst[s][j] = lst[s][j + 1];
        lst[s][LLEN - 1] = 0u;
      }
      head = lst[s][0];
    }
  }
  __syncthreads();

  // rank-select top-NS1 of 192 (keys unique) -> global key buffer
  {
    const int row = tid >> 4, l16 = tid & 15;
    unsigned myk[12];
    int rank[12];
    #pragma unroll
    for (int j = 0; j < 12; ++j) {
      myk[j]  = u1.mg[row][l16 + 16 * j];
      rank[j] = 0;
    }
    for (int e = 0; e < MG; ++e) {
      unsigned k2 = u1.mg[row][e];
      #pragma unroll
      for (int j = 0; j < 12; ++j) rank[j] += (k2 > myk[j]) ? 1 : 0;
    }
    #pragma unroll
    for (int j = 0; j < 12; ++j)
      if (rank[j] < NS1)
        gkeys[(size_t)(mb + row) * MRG + hs * NS1 + rank[j]] = myk[j];
  }
}

// ---------------- Kernel B2: merge halves + exact f64 rerank + decode ----
__global__ __launch_bounds__(512) void sae_dec(
    const float* __restrict__ x,    const float* __restrict__ Wenc,
    const float* __restrict__ benc, const float* __restrict__ Wdec,
    const float* __restrict__ bdec, const unsigned* __restrict__ gkeys,
    float* __restrict__ out)
{
  __shared__ unsigned mk[BM][MRG];
  __shared__ __align__(16) float xf[BM][XF_LD];
  __shared__ float tv[BM][NS2];
  __shared__ int   ti[BM][NS2];

  const int tid = (int)threadIdx.x;
  const int mb  = (int)blockIdx.x * BM;

  for (int i = tid; i < BM * MRG; i += 512)
    mk[i / MRG][i % MRG] = gkeys[(size_t)mb * MRG + i];

  {  // stage exact f32 sae_in rows
    const int r = tid >> 4, seg = tid & 15;
    const float* xs = x + (size_t)(mb + r) * DIN + seg * 16;
    const float* bs = bdec + seg * 16;
    #pragma unroll
    for (int j = 0; j < 4; ++j) {
      float4 xv = *(const float4*)(xs + 4 * j);
      float4 bv = *(const float4*)(bs + 4 * j);
      float4 d;
      d.x = xv.x - bv.x; d.y = xv.y - bv.y; d.z = xv.z - bv.z; d.w = xv.w - bv.w;
      *(float4*)&xf[r][seg * 16 + 4 * j] = d;
    }
  }
  __syncthreads();

  // merge: rank-select top-NS2 of 96 (keys unique)
  {
    const int row = tid >> 4, l16 = tid & 15;
    unsigned myk[6];
    int rk[6];
    #pragma unroll
    for (int j = 0; j < 6; ++j) {
      myk[j] = mk[row][l16 + 16 * j];
      rk[j]  = 0;
    }
    for (int e = 0; e < MRG; ++e) {
      unsigned k2 = mk[row][e];
      #pragma unroll
      for (int j = 0; j < 6; ++j) rk[j] += (k2 > myk[j]) ? 1 : 0;
    }
    #pragma unroll
    for (int j = 0; j < 6; ++j)
      if (rk[j] < NS2) ti[row][rk[j]] = 8191 - (int)(myk[j] & 0xFFFFu);
  }
  __syncthreads();

  // exact f64 rerank of NS2 candidates/row; 4 threads per (row,cand) pair
  {
    const int sub = tid & 3, pidx = tid >> 2;   // 128 pair-slots per pass
    for (int j = 0; j < (BM * NS2) / 128; ++j) {
      int pp = j * 128 + pidx;
      int row = pp / NS2, cand = pp - row * NS2;
      int h = ti[row][cand];
      const float* wp = Wenc + (size_t)h * DIN + sub * 64;
      const float* xp = &xf[row][sub * 64];
      double accd = 0.0;
      #pragma unroll
      for (int kk = 0; kk < 16; ++kk) {
        float4 w  = *(const float4*)(wp + 4 * kk);
        float4 xv = *(const float4*)(xp + 4 * kk);
        accd += (double)xv.x * (double)w.x;
        accd += (double)xv.y * (double)w.y;
        accd += (double)xv.z * (double)w.z;
        accd += (double)xv.w * (double)w.w;
      }
      accd += __shfl_down(accd, 2, 4);
      accd += __shfl_down(accd, 1, 4);
      if (sub == 0) {
        float ev = (float)accd + benc[h];
        ev = ev > 0.0f ? ev : 0.0f;   // relu before ranking (matches ref)
        tv[row][cand] = ev;
      }
    }
  }
  __syncthreads();
  if (tid < BM) {  // exact top-32 of NS2 (value desc, idx asc)
    float* tvr = tv[tid];
    int*   tir = ti[tid];
    for (int s = 0; s < TOPK; ++s) {
      float bv = tvr[s]; int bi = tir[s]; int bp = s;
      for (int t2 = s + 1; t2 < NS2; ++t2) {
        float v2 = tvr[t2]; int i2 = tir[t2];
        if (v2 > bv || (v2 == bv && (unsigned)i2 < (unsigned)bi)) {
          bv = v2; bi = i2; bp = t2;
        }
      }
      if (bp != s) {
        tvr[bp] = tvr[s]; tir[bp] = tir[s];
        tvr[s] = bv; tir[s] = bi;
      }
    }
  }
  __syncthreads();

  // decode: out[b,:] = sum z_k * W_dec[idx_k,:] + b_dec  (all f32)
  {
    const int r = tid >> 4, seg = tid & 15, d0 = seg * 16;
    float od[16];
    #pragma unroll
    for (int j = 0; j < 4; ++j) {
      float4 b = *(const float4*)(bdec + d0 + 4 * j);
      od[4 * j] = b.x; od[4 * j + 1] = b.y; od[4 * j + 2] = b.z; od[4 * j + 3] = b.w;
    }
    for (int s = 0; s < TOPK; ++s) {
      float v = tv[r][s];
      if (!(v > 0.0f)) break;    // sorted desc
      int h = ti[r][s];
      const float* wp = Wdec + (size_t)h * DIN + d0;
      #pragma unroll
      for (int j = 0; j < 4; ++j) {
        float4 w = *(const float4*)(wp + 4 * j);
        od[4 * j]     += v * w.x;
        od[4 * j + 1] += v * w.y;
        od[4 * j + 2] += v * w.z;
        od[4 * j + 3] += v * w.w;
      }
    }
    float* op = out + (size_t)(mb + r) * DIN + d0;
    #pragma unroll
    for (int j = 0; j < 4; ++j) {
      float4 o;
      o.x = od[4 * j]; o.y = od[4 * j + 1]; o.z = od[4 * j + 2]; o.w = od[4 * j + 3];
      *(float4*)(op + 4 * j) = o;
    }
  }
}

extern "C" void kernel_launch(void* const* d_in, const int* in_sizes, int n_in,
                              void* d_out, int out_size, void* d_ws, size_t ws_size,
                              hipStream_t stream) {
  const float* x    = (const float*)d_in[0];
  const float* Wenc = (const float*)d_in[1];
  const float* benc = (const float*)d_in[2];
  const float* Wdec = (const float*)d_in[3];
  const float* bdec = (const float*)d_in[4];
  float* out = (float*)d_out;
  unsigned short* wsb = (unsigned short*)d_ws;                 // 4 MiB bf16 fragments
  unsigned* gkeys = (unsigned*)((char*)d_ws + GK_OFF);         // 3 MiB keys

  wenc_cast<<<dim3((HID * DIN / 8) / 512), dim3(512), 0, stream>>>(Wenc, wsb);
  sae_enc<<<dim3(2 * BATCH / BM), dim3(512), 0, stream>>>(x, benc, bdec, wsb, gkeys);
  sae_dec<<<dim3(BATCH / BM), dim3(512), 0, stream>>>(x, Wenc, benc, Wdec, bdec, gkeys, out);
}